// Round 11
// baseline (44.502 us; speedup 1.0000x reference)
//
#include <hip/hip_runtime.h>

// NonLocalMean: x (4,64,128,128) fp32, K=7 (rad 3), HEADS=4 -> mid=16.
// w_p = exp(-||n_q - c||^2) <= 1 (exact c in both dot and ||c||^2, so the
// softmax max is 0 at the center even with quantized neighbors) -> plain
// sum. out = x + (sum w_p n_p)/(sum w_p); zero-padded OOB patches are zero
// vectors contributing exp(-||c||^2).
//
// R11: bank-math audit showed the real wave footprint (4 rows x 16 lx)
// made every per-visit nn b32 read ~8-way conflicted with even strides,
// and LDS+VALU pipe budgets ADD (~35us) at 4 waves/SIMD. Fixes:
//  1) bf16 records, PSTRD=12 (48B, 16B-aligned): 2 x ds_read_b128 + b32
//     per visit (vs fp32's 4+1).
//  2) visit-split: lane pair (2i,2i+1) = same pixel, wy parity h. s/acc
//     are linear -> DPP quad_perm xor1 combine at the end. Doubles waves
//     (shorter chains -> overlap) AND makes adjacent lanes read the SAME
//     LDS address -> broadcast, halving unique addrs: nn read ~2-way.
//  3) nn and cc stored pre-scaled by log2e -> native exp2, 1 fma/visit.
// No launch_bounds clamp (R4/R6/R8: caps => spill disaster). Loops rolled.

#define TW    16
#define RAD   3
#define HWD   22                 // 16 + 6
#define NPIX  (HWD * HWD)        // 484
#define MID   16
#define PSTRD 12                 // dwords per record (48 B): 8 ch-pairs + nnL
#define IMG   128
#define PLANE (IMG * IMG)
#define LOG2E 1.4426950408889634f

__device__ __forceinline__ unsigned bf16rne(float v) {
    unsigned u = __float_as_uint(v);
    u += 0x7fffu + ((u >> 16) & 1u);
    return u >> 16;
}
__device__ __forceinline__ float bl(unsigned u) { return __uint_as_float(u << 16); }
__device__ __forceinline__ float bh(unsigned u) { return __uint_as_float(u & 0xffff0000u); }

// lane-pair (xor 1) exchange + add via full-rate DPP quad_perm(1,0,3,2)
__device__ __forceinline__ float xor1_sum(float v) {
    int o = __builtin_amdgcn_update_dpp(0, __float_as_int(v),
                                        0xB1 /*quad_perm 1,0,3,2*/,
                                        0xF, 0xF, true);
    return v + __int_as_float(o);
}

__global__ __launch_bounds__(512)
void nlm_kernel(const float* __restrict__ x, float* __restrict__ out) {
    const int g   = blockIdx.z & 3;
    const int b   = blockIdx.z >> 2;
    const int tx0 = blockIdx.x * TW;
    const int ty0 = blockIdx.y * TW;

    __shared__ __align__(16) unsigned recd[NPIX * PSTRD];   // 23,232 B

    const int tid = threadIdx.x;          // 0..511
    const float* xb = x + (size_t)(b * 64 + g * MID) * PLANE;

    // ---- stage halo: bf16-packed channels + log2e*||n_q||^2 at dword 8 ----
    if (tid < NPIX) {
        const int yy = tid / HWD;
        const int xx = tid - yy * HWD;
        const int gy = ty0 + yy - RAD;
        const int gx = tx0 + xx - RAD;
        const bool in = ((unsigned)gy < (unsigned)IMG) & ((unsigned)gx < (unsigned)IMG);
        const float* p = xb + gy * IMG + gx;
        unsigned pk[8];
        float ss = 0.f;
        #pragma unroll
        for (int k = 0; k < 8; ++k) {
            const float v0 = in ? p[(2 * k) * PLANE] : 0.f;
            const float v1 = in ? p[(2 * k + 1) * PLANE] : 0.f;
            const unsigned q0 = bf16rne(v0);
            const unsigned q1 = bf16rne(v1);
            pk[k] = q0 | (q1 << 16);
            const float r0 = __uint_as_float(q0 << 16);
            const float r1 = __uint_as_float(q1 << 16);
            ss = fmaf(r0, r0, ss);
            ss = fmaf(r1, r1, ss);
        }
        unsigned* rp = &recd[tid * PSTRD];
        *reinterpret_cast<uint4*>(rp + 0) = make_uint4(pk[0], pk[1], pk[2], pk[3]);
        *reinterpret_cast<uint4*>(rp + 4) = make_uint4(pk[4], pk[5], pk[6], pk[7]);
        rp[8] = __float_as_uint(ss * LOG2E);
    }
    __syncthreads();

    // ---- main: lane pair = one pixel; h = wy parity ----
    const int h   = tid & 1;
    const int pix = tid >> 1;             // 0..255
    const int lx  = pix & 15;
    const int ly  = pix >> 4;

    // exact fp32 center from global (residual + dot accuracy)
    const float* cp = xb + (ty0 + ly) * IMG + (tx0 + lx);
    float ctr[MID];
    #pragma unroll
    for (int c = 0; c < MID; ++c) ctr[c] = cp[c * PLANE];
    float c0 = 0.f, c1 = 0.f;
    #pragma unroll
    for (int c = 0; c < MID; c += 2) {
        c0 = fmaf(ctr[c], ctr[c], c0);
        c1 = fmaf(ctr[c + 1], ctr[c + 1], c1);
    }
    const float ccL = (c0 + c1) * LOG2E;

    float acc[MID];
    #pragma unroll
    for (int c = 0; c < MID; ++c) acc[c] = 0.f;
    float s = 0.f;

    // h=0: wy 0,2,4,6 (28 visits); h=1: wy 1,3,5 (21 visits)
    #pragma unroll 1
    for (int wy = h; wy < 7; wy += 2) {
        const unsigned* rp = &recd[((ly + wy) * HWD + lx) * PSTRD];
        #pragma unroll 1
        for (int wx = 0; wx < 7; ++wx) {
            const uint4 q0 = *reinterpret_cast<const uint4*>(rp + 0);
            const uint4 q1 = *reinterpret_cast<const uint4*>(rp + 4);
            const float nnL = __uint_as_float(rp[8]);
            float nb[MID];
            nb[0]  = bl(q0.x); nb[1]  = bh(q0.x);
            nb[2]  = bl(q0.y); nb[3]  = bh(q0.y);
            nb[4]  = bl(q0.z); nb[5]  = bh(q0.z);
            nb[6]  = bl(q0.w); nb[7]  = bh(q0.w);
            nb[8]  = bl(q1.x); nb[9]  = bh(q1.x);
            nb[10] = bl(q1.y); nb[11] = bh(q1.y);
            nb[12] = bl(q1.z); nb[13] = bh(q1.z);
            nb[14] = bl(q1.w); nb[15] = bh(q1.w);

            float d0 = 0.f, d1 = 0.f, d2 = 0.f, d3 = 0.f;
            #pragma unroll
            for (int c = 0; c < MID; c += 4) {
                d0 = fmaf(nb[c + 0], ctr[c + 0], d0);
                d1 = fmaf(nb[c + 1], ctr[c + 1], d1);
                d2 = fmaf(nb[c + 2], ctr[c + 2], d2);
                d3 = fmaf(nb[c + 3], ctr[c + 3], d3);
            }
            const float dot = (d0 + d1) + (d2 + d3);
            const float w = exp2f(fmaf(2.f * LOG2E, dot, -(nnL + ccL)));
            s += w;
            #pragma unroll
            for (int c = 0; c < MID; ++c) acc[c] = fmaf(w, nb[c], acc[c]);
            rp += PSTRD;
        }
    }

    // ---- lane-pair combine (s, acc are linear in visits) ----
    s = xor1_sum(s);
    #pragma unroll
    for (int c = 0; c < MID; ++c) acc[c] = xor1_sum(acc[c]);

    const float inv = 1.f / s;
    // lane h writes channels 8h..8h+7 (both lanes hold the full sums)
    float* ob = out + (size_t)(b * 64 + g * MID + 8 * h) * PLANE
                    + (size_t)(ty0 + ly) * IMG + (tx0 + lx);
    #pragma unroll
    for (int c = 0; c < 8; ++c)
        ob[c * PLANE] = fmaf(acc[8 * h + c], inv, ctr[8 * h + c]);
}

extern "C" void kernel_launch(void* const* d_in, const int* in_sizes, int n_in,
                              void* d_out, int out_size, void* d_ws, size_t ws_size,
                              hipStream_t stream) {
    const float* x = (const float*)d_in[0];
    float* out = (float*)d_out;
    dim3 grid(IMG / TW, IMG / TW, 16);   // 8 x 8 x (B=4 * HEADS=4) = 1024 blocks
    nlm_kernel<<<grid, 512, 0, stream>>>(x, out);
}